// Round 2
// baseline (2214.846 us; speedup 1.0000x reference)
//
#include <hip/hip_runtime.h>
#include <math.h>

// ---- problem constants ----
#define NB    160          // BS*CS
#define NANC  3            // NA
#define NN    14196        // total cells across scales
#define STOT  (NB*NANC*NN) // 6,814,080 dense grid entries
#define EPSF  1e-7f
#define INSZ  832.0f

// scale boundaries in n: [0,676) s0, [676,3380) s1, [3380,14196) s2
#define S1OFF 676
#define S2OFF 3380

#define IGN_BIT (1 << 16)

__device__ __forceinline__ float sigmoidf_(float z) {
    return 1.0f / (1.0f + expf(-z));
}

// Phase 1: one thread per (b, scale); replay b's 50 targets in order.
// Scales write disjoint n-ranges, so per-cell RMW is single-owner (no atomics).
// Last-write-wins over tt matches JAX's in-order scatter-set.
// cell encoding: bits [0:16) = writer target id + 1 (0 = none); bit 16 = ign.
__global__ void build_targets_kernel(const float* __restrict__ tgt,
                                     const float* __restrict__ anchors,
                                     int* __restrict__ cells) {
    int bs3 = blockIdx.x * blockDim.x + threadIdx.x;
    if (bs3 >= NB * 3) return;
    int s = bs3 % 3;
    int b = bs3 / 3;
    const int s0s[3] = {0, S1OFF, S2OFF};
    const int fws[3] = {26, 52, 104};
    const int s0 = s0s[s];
    const int fw = fws[s];
    float aw0 = anchors[6*s + 0], ah0 = anchors[6*s + 1];
    float aw1 = anchors[6*s + 2], ah1 = anchors[6*s + 3];
    float aw2 = anchors[6*s + 4], ah2 = anchors[6*s + 5];
    for (int tt = 0; tt < 50; ++tt) {
        int t = b * 50 + tt;
        float txn = tgt[t*5 + 1];
        float tyn = tgt[t*5 + 2];
        float twn = tgt[t*5 + 3];
        float thn = tgt[t*5 + 4];
        if (!(twn > 0.0f)) continue;          // valid = tb[:,3] > 0
        float gw = twn * INSZ;
        float gh = thn * INSZ;
        float gx = txn * (float)fw;
        float gy = tyn * (float)fw;           // fh == fw for all scales
        int gi = (int)gx;
        int gj = (int)gy;
        int loc = gj * fw + gi;
        float iou0, iou1, iou2;
        {
            float inter = fminf(gw, aw0) * fminf(gh, ah0);
            iou0 = inter / (gw*gh + aw0*ah0 - inter);
            inter = fminf(gw, aw1) * fminf(gh, ah1);
            iou1 = inter / (gw*gh + aw1*ah1 - inter);
            inter = fminf(gw, aw2) * fminf(gh, ah2);
            iou2 = inter / (gw*gh + aw2*ah2 - inter);
        }
        // argmax, first max wins (matches jnp.argmax ties)
        int best_a = 0;
        float best = iou0;
        if (iou1 > best) { best = iou1; best_a = 1; }
        if (iou2 > best) { best = iou2; best_a = 2; }
        size_t base = (size_t)b * NANC * NN + s0 + loc;
        if (iou0 > 0.5f) cells[base]            |= IGN_BIT;
        if (iou1 > 0.5f) cells[base + NN]       |= IGN_BIT;
        if (iou2 > 0.5f) cells[base + 2*NN]     |= IGN_BIT;
        size_t wi = base + (size_t)best_a * NN;
        cells[wi] = (cells[wi] & IGN_BIT) | (t + 1);
    }
}

// Phase 2: dense reduction over all (b, a, n) cells.
// acc[0]=n_obj  acc[1]=n_noobj  acc[2]=coord_sq  acc[3]=obj*-log(p)
// acc[4]=noobj*-log(1-p)  acc[5]=cls (lse - logit)
__global__ void loss_reduce_kernel(const float* __restrict__ out,
                                   const float* __restrict__ tgt,
                                   const float* __restrict__ anchors,
                                   const int* __restrict__ cells,
                                   double* __restrict__ acc) {
    int idx = blockIdx.x * blockDim.x + threadIdx.x;
    float c_obj = 0.f, c_noobj = 0.f, c_coord = 0.f,
          c_onlp = 0.f, c_nnl = 0.f, c_cls = 0.f;

    if (idx < STOT) {
        int n  = idx % NN;
        int ba = idx / NN;
        int a  = ba % NANC;
        int bI = ba / NANC;

        const float* base = out + ((size_t)bI*18 + a*6) * NN + n;
        float xv   = sigmoidf_(base[0]);
        float yv   = sigmoidf_(base[(size_t)NN]);
        float wv   = base[(size_t)2*NN];
        float hv   = base[(size_t)3*NN];
        float conf = sigmoidf_(base[(size_t)4*NN]);
        float p = fminf(fmaxf(conf, EPSF), 1.0f - EPSF);

        int cell = cells[idx];
        int t = (cell & 0xFFFF) - 1;
        bool isign = (cell & IGN_BIT) != 0;

        if (t >= 0) {
            c_obj = 1.0f;
            int s, fw;
            if (n < S1OFF)      { s = 0; fw = 26;  }
            else if (n < S2OFF) { s = 1; fw = 52;  }
            else                { s = 2; fw = 104; }
            float gx = tgt[t*5 + 1] * (float)fw;
            float gy = tgt[t*5 + 2] * (float)fw;
            float gw = tgt[t*5 + 3] * INSZ;
            float gh = tgt[t*5 + 4] * INSZ;
            float tx = gx - floorf(gx);
            float ty = gy - floorf(gy);
            float aw = anchors[6*s + 2*a];
            float ah = anchors[6*s + 2*a + 1];
            float tw = logf(fmaxf(gw / aw, EPSF));
            float th = logf(fmaxf(gh / ah, EPSF));
            c_coord = (xv-tx)*(xv-tx) + (yv-ty)*(yv-ty)
                    + (wv-tw)*(wv-tw) + (hv-th)*(hv-th);
            c_onlp = -logf(p);

            // class term: log-softmax across the CS=20 axis at (bs, a, n)
            int bs = bI / 20;
            float mylogit = base[(size_t)5*NN];
            float mx = -INFINITY;
            float logits[20];
            #pragma unroll
            for (int c = 0; c < 20; ++c) {
                logits[c] = out[(((size_t)(bs*20 + c))*18 + a*6 + 5) * NN + n];
                mx = fmaxf(mx, logits[c]);
            }
            float se = 0.0f;
            #pragma unroll
            for (int c = 0; c < 20; ++c) se += expf(logits[c] - mx);
            float lse = mx + logf(se);
            c_cls = lse - mylogit;
        } else if (!isign) {
            c_noobj = 1.0f;
            c_nnl = -logf(1.0f - p);
        }
    }

    // block reduction: wave shuffle (64-wide) then LDS across 4 waves
    float vals[6] = {c_obj, c_noobj, c_coord, c_onlp, c_nnl, c_cls};
    #pragma unroll
    for (int k = 0; k < 6; ++k) {
        float v = vals[k];
        #pragma unroll
        for (int o = 32; o > 0; o >>= 1) v += __shfl_down(v, o, 64);
        vals[k] = v;
    }
    __shared__ float sdata[4][6];
    int wave = threadIdx.x >> 6;
    int lane = threadIdx.x & 63;
    if (lane == 0) {
        #pragma unroll
        for (int k = 0; k < 6; ++k) sdata[wave][k] = vals[k];
    }
    __syncthreads();
    if (threadIdx.x == 0) {
        #pragma unroll
        for (int k = 0; k < 6; ++k) {
            float s = sdata[0][k] + sdata[1][k] + sdata[2][k] + sdata[3][k];
            atomicAdd(&acc[k], (double)s);
        }
    }
}

__global__ void finalize_kernel(const double* __restrict__ acc,
                                float* __restrict__ out) {
    double n_obj   = fmax(acc[0], 1.0);
    double n_noobj = fmax(acc[1], 1.0);
    double loss = acc[2] / n_obj           // COORD_SCALE * (x+y+w+h)
                + acc[3] / n_obj           // OBJ_SCALE * obj conf
                + 100.0 * acc[4] / n_noobj // NOOBJ_SCALE * noobj conf
                + acc[5] / n_obj;          // CLASS_SCALE * cls
    out[0] = (float)loss;
}

extern "C" void kernel_launch(void* const* d_in, const int* in_sizes, int n_in,
                              void* d_out, int out_size, void* d_ws, size_t ws_size,
                              hipStream_t stream) {
    const float* output  = (const float*)d_in[0];
    const float* target  = (const float*)d_in[1];
    const float* anchors = (const float*)d_in[2];
    float* out = (float*)d_out;

    // workspace layout
    int*    cells = (int*)d_ws;                                   // STOT*4 B
    double* acc   = (double*)((char*)d_ws + (size_t)STOT*4);      // 48 B (27256320 % 8 == 0)

    hipMemsetAsync(cells, 0x00, (size_t)STOT * 4, stream);
    hipMemsetAsync(acc, 0x00, 6 * sizeof(double), stream);

    build_targets_kernel<<<2, 256, 0, stream>>>(target, anchors, cells);

    int threads = 256;
    int blocks = (STOT + threads - 1) / threads;
    loss_reduce_kernel<<<blocks, threads, 0, stream>>>(output, target, anchors,
                                                       cells, acc);
    finalize_kernel<<<1, 1, 0, stream>>>(acc, out);
}

// Round 3
// 293.716 us; speedup vs baseline: 7.5408x; 7.5408x over previous
//
#include <hip/hip_runtime.h>
#include <math.h>

// ---- problem constants ----
#define NB    160          // BS*CS
#define NANC  3            // NA
#define NN    14196        // total cells across scales
#define STOT  (NB*NANC*NN) // 6,814,080 dense grid entries
#define NQ    (STOT/4)     // 1,703,520 quads (4 | NN, scale bounds are x4)
#define EPSF  1e-7f
#define INSZ  832.0f

// scale boundaries in n: [0,676) s0, [676,3380) s1, [3380,14196) s2
#define S1OFF 676
#define S2OFF 3380

#define NBLK  2048         // reduce grid (fixed); partials are per-block

// workspace layout (bytes)
#define WRITER_BYTES ((size_t)STOT * 2)              // 13,628,160
#define IGN_WORDS    (STOT / 32)                     // 212,940
#define IGN_BYTES    ((size_t)IGN_WORDS * 4)         // 851,760
#define PART_OFF     (WRITER_BYTES + IGN_BYTES)      // 14,479,920 (8-aligned)

__device__ __forceinline__ float sigmoidf_(float z) {
    return 1.0f / (1.0f + expf(-z));
}

// Phase 1: one thread per (b, scale); replay b's 50 targets in order.
// Scales write disjoint n-ranges; writer stores are 2B (byte-enable safe),
// ign is a bitmask via atomicOr (words can straddle scale boundaries).
// Last-write-wins over tt matches JAX's in-order scatter-set (verified: absmax 0).
__global__ void build_targets_kernel(const float* __restrict__ tgt,
                                     const float* __restrict__ anchors,
                                     unsigned short* __restrict__ writer,
                                     unsigned int* __restrict__ ign) {
    int bs3 = blockIdx.x * blockDim.x + threadIdx.x;
    if (bs3 >= NB * 3) return;
    int s = bs3 % 3;
    int b = bs3 / 3;
    const int s0s[3] = {0, S1OFF, S2OFF};
    const int fws[3] = {26, 52, 104};
    const int s0 = s0s[s];
    const int fw = fws[s];
    float aw0 = anchors[6*s + 0], ah0 = anchors[6*s + 1];
    float aw1 = anchors[6*s + 2], ah1 = anchors[6*s + 3];
    float aw2 = anchors[6*s + 4], ah2 = anchors[6*s + 5];
    for (int tt = 0; tt < 50; ++tt) {
        int t = b * 50 + tt;
        float txn = tgt[t*5 + 1];
        float tyn = tgt[t*5 + 2];
        float twn = tgt[t*5 + 3];
        float thn = tgt[t*5 + 4];
        if (!(twn > 0.0f)) continue;          // valid = tb[:,3] > 0
        float gw = twn * INSZ;
        float gh = thn * INSZ;
        float gx = txn * (float)fw;
        float gy = tyn * (float)fw;           // fh == fw for all scales
        int gi = (int)gx;
        int gj = (int)gy;
        int loc = gj * fw + gi;
        float inter, iou0, iou1, iou2;
        inter = fminf(gw, aw0) * fminf(gh, ah0);
        iou0 = inter / (gw*gh + aw0*ah0 - inter);
        inter = fminf(gw, aw1) * fminf(gh, ah1);
        iou1 = inter / (gw*gh + aw1*ah1 - inter);
        inter = fminf(gw, aw2) * fminf(gh, ah2);
        iou2 = inter / (gw*gh + aw2*ah2 - inter);
        // argmax, first max wins (matches jnp.argmax ties)
        int best_a = 0;
        float best = iou0;
        if (iou1 > best) { best = iou1; best_a = 1; }
        if (iou2 > best) { best = iou2; best_a = 2; }
        size_t base = (size_t)b * NANC * NN + s0 + loc;
        if (iou0 > 0.5f) atomicOr(&ign[(base)        >> 5], 1u << ((base)        & 31));
        if (iou1 > 0.5f) atomicOr(&ign[(base+NN)     >> 5], 1u << ((base+NN)     & 31));
        if (iou2 > 0.5f) atomicOr(&ign[(base+2*NN)   >> 5], 1u << ((base+2*NN)   & 31));
        writer[base + (size_t)best_a * NN] = (unsigned short)(t + 1);
    }
}

// Phase 2: grid-stride dense reduction over quads of (b,a,n) cells.
// Only the conf channel is read densely; x/y/w/h/cls are gathered at the
// ~24k obj cells. Partials written non-atomically per block.
// acc[0]=n_obj acc[1]=n_noobj acc[2]=coord_sq acc[3]=obj*-log(p)
// acc[4]=noobj*-log(1-p) acc[5]=cls (lse - logit)
__global__ __launch_bounds__(256)
void loss_reduce_kernel(const float* __restrict__ out,
                        const float* __restrict__ tgt,
                        const float* __restrict__ anchors,
                        const unsigned short* __restrict__ writer,
                        const unsigned int* __restrict__ ign,
                        float* __restrict__ partials) {
    int gid = blockIdx.x * blockDim.x + threadIdx.x;
    const int gstride = NBLK * 256;
    float acc0 = 0.f, acc1 = 0.f, acc2 = 0.f, acc3 = 0.f, acc4 = 0.f, acc5 = 0.f;

    for (int q = gid; q < NQ; q += gstride) {
        int flat = q << 2;
        int n  = flat % NN;           // 4 | NN: whole quad shares (bI, a)
        int ba = flat / NN;
        int a  = ba % NANC;
        int bI = ba / NANC;

        const float* rowbase = out + ((size_t)bI*18 + a*6) * NN + n;
        float4 conf4 = *(const float4*)(rowbase + (size_t)4*NN);
        ushort4 w4v  = *(const ushort4*)(writer + flat);
        unsigned ignbits = (ign[flat >> 5] >> (flat & 31)) & 0xF;
        unsigned short wv[4] = {w4v.x, w4v.y, w4v.z, w4v.w};
        float cf[4] = {conf4.x, conf4.y, conf4.z, conf4.w};

        // scale of this quad (boundaries 676/3380 are multiples of 4)
        int s, fw;
        if (n < S1OFF)      { s = 0; fw = 26;  }
        else if (n < S2OFF) { s = 1; fw = 52;  }
        else                { s = 2; fw = 104; }

        #pragma unroll
        for (int e = 0; e < 4; ++e) {
            float p = fminf(fmaxf(sigmoidf_(cf[e]), EPSF), 1.0f - EPSF);
            int t = (int)wv[e] - 1;
            if (t >= 0) {
                int ne = n + e;
                acc0 += 1.0f;
                float gx = tgt[t*5 + 1] * (float)fw;
                float gy = tgt[t*5 + 2] * (float)fw;
                float gw = tgt[t*5 + 3] * INSZ;
                float gh = tgt[t*5 + 4] * INSZ;
                float tx = gx - floorf(gx);
                float ty = gy - floorf(gy);
                float aw = anchors[6*s + 2*a];
                float ah = anchors[6*s + 2*a + 1];
                float tw = logf(fmaxf(gw / aw, EPSF));
                float th = logf(fmaxf(gh / ah, EPSF));
                const float* cb = out + ((size_t)bI*18 + a*6) * NN + ne;
                float xv = sigmoidf_(cb[0]);
                float yv = sigmoidf_(cb[(size_t)NN]);
                float wvv = cb[(size_t)2*NN];
                float hv  = cb[(size_t)3*NN];
                acc2 += (xv-tx)*(xv-tx) + (yv-ty)*(yv-ty)
                      + (wvv-tw)*(wvv-tw) + (hv-th)*(hv-th);
                acc3 += -logf(p);
                // class term: log-softmax across the CS=20 axis
                int bs = bI / 20;
                float mylogit = cb[(size_t)5*NN];
                float mx = -INFINITY;
                float logits[20];
                #pragma unroll
                for (int c = 0; c < 20; ++c) {
                    logits[c] = out[(((size_t)(bs*20 + c))*18 + a*6 + 5) * NN + ne];
                    mx = fmaxf(mx, logits[c]);
                }
                float se = 0.0f;
                #pragma unroll
                for (int c = 0; c < 20; ++c) se += expf(logits[c] - mx);
                acc5 += (mx + logf(se)) - mylogit;
            } else if (!((ignbits >> e) & 1)) {
                acc1 += 1.0f;
                acc4 += -logf(1.0f - p);
            }
        }
    }

    // block reduction: wave shuffle (64-wide) then LDS across 4 waves
    float vals[6] = {acc0, acc1, acc2, acc3, acc4, acc5};
    #pragma unroll
    for (int k = 0; k < 6; ++k) {
        float v = vals[k];
        #pragma unroll
        for (int o = 32; o > 0; o >>= 1) v += __shfl_down(v, o, 64);
        vals[k] = v;
    }
    __shared__ float sdata[4][6];
    int wave = threadIdx.x >> 6;
    int lane = threadIdx.x & 63;
    if (lane == 0) {
        #pragma unroll
        for (int k = 0; k < 6; ++k) sdata[wave][k] = vals[k];
    }
    __syncthreads();
    if (threadIdx.x == 0) {
        #pragma unroll
        for (int k = 0; k < 6; ++k)
            partials[k*NBLK + blockIdx.x] =
                sdata[0][k] + sdata[1][k] + sdata[2][k] + sdata[3][k];
    }
}

__global__ void finalize_kernel(const float* __restrict__ partials,
                                float* __restrict__ out) {
    int tid = threadIdx.x;
    double loc[6] = {0,0,0,0,0,0};
    for (int i = tid; i < NBLK; i += 256) {
        #pragma unroll
        for (int k = 0; k < 6; ++k) loc[k] += (double)partials[k*NBLK + i];
    }
    #pragma unroll
    for (int k = 0; k < 6; ++k) {
        double v = loc[k];
        #pragma unroll
        for (int o = 32; o > 0; o >>= 1) v += __shfl_down(v, o, 64);
        loc[k] = v;
    }
    __shared__ double sd[4][6];
    int wave = tid >> 6;
    int lane = tid & 63;
    if (lane == 0) {
        #pragma unroll
        for (int k = 0; k < 6; ++k) sd[wave][k] = loc[k];
    }
    __syncthreads();
    if (tid == 0) {
        double a[6];
        #pragma unroll
        for (int k = 0; k < 6; ++k)
            a[k] = sd[0][k] + sd[1][k] + sd[2][k] + sd[3][k];
        double n_obj   = fmax(a[0], 1.0);
        double n_noobj = fmax(a[1], 1.0);
        double loss = a[2] / n_obj            // COORD_SCALE * (x+y+w+h)
                    + a[3] / n_obj            // OBJ_SCALE * obj conf
                    + 100.0 * a[4] / n_noobj  // NOOBJ_SCALE * noobj conf
                    + a[5] / n_obj;           // CLASS_SCALE * cls
        out[0] = (float)loss;
    }
}

extern "C" void kernel_launch(void* const* d_in, const int* in_sizes, int n_in,
                              void* d_out, int out_size, void* d_ws, size_t ws_size,
                              hipStream_t stream) {
    const float* output  = (const float*)d_in[0];
    const float* target  = (const float*)d_in[1];
    const float* anchors = (const float*)d_in[2];
    float* out = (float*)d_out;

    unsigned short* writer   = (unsigned short*)d_ws;
    unsigned int*   ign      = (unsigned int*)((char*)d_ws + WRITER_BYTES);
    float*          partials = (float*)((char*)d_ws + PART_OFF);

    // writer + ign are contiguous and both zero-initialized
    hipMemsetAsync(d_ws, 0x00, PART_OFF, stream);

    build_targets_kernel<<<2, 256, 0, stream>>>(target, anchors, writer, ign);

    loss_reduce_kernel<<<NBLK, 256, 0, stream>>>(output, target, anchors,
                                                 writer, ign, partials);
    finalize_kernel<<<1, 256, 0, stream>>>(partials, out);
}